// Round 17
// baseline (225.183 us; speedup 1.0000x reference)
//
#include <hip/hip_runtime.h>
#include <hip/hip_bf16.h>
#include <math.h>

typedef __bf16 bf16x8 __attribute__((ext_vector_type(8)));
typedef float f32x4 __attribute__((ext_vector_type(4)));

__device__ __forceinline__ __hip_bfloat16 f2bf(float v){ return __float2bfloat16(v); }

// async global->LDS, 16B per lane; LDS dest is wave-uniform base (lane i writes base+i*16),
// global source is PER-LANE (swizzled layouts via pre-swizzled source addresses).
__device__ __forceinline__ void gload16(const void* g, void* l){
  __builtin_amdgcn_global_load_lds(
      (const __attribute__((address_space(1))) void*)g,
      (__attribute__((address_space(3))) void*)l, 16, 0, 0);
}

// ---------------- LayerNorm body over C=768 ----------------
__device__ __forceinline__ void ln_body(const float* rp, const float* g, const float* b,
                                        __hip_bfloat16* op, int t){
  float x0 = rp[t], x1 = rp[t+256], x2 = rp[t+512];
  float s = x0+x1+x2, ss = x0*x0+x1*x1+x2*x2;
#pragma unroll
  for(int o=32;o>0;o>>=1){ s += __shfl_down(s,o); ss += __shfl_down(ss,o); }
  __shared__ float red[10];
  if((t&63)==0){ red[t>>6]=s; red[4+(t>>6)]=ss; }
  __syncthreads();
  if(t==0){
    float S=red[0]+red[1]+red[2]+red[3], SS=red[4]+red[5]+red[6]+red[7];
    float m=S*(1.f/768.f);
    red[8]=m; red[9]=SS*(1.f/768.f)-m*m;
  }
  __syncthreads();
  float m=red[8], r=rsqrtf(red[9]+1e-5f);
  op[t]     = f2bf((x0-m)*r*g[t]     + b[t]);
  op[t+256] = f2bf((x1-m)*r*g[t+256] + b[t+256]);
  op[t+512] = f2bf((x2-m)*r*g[t+512] + b[t+512]);
}

// ---------------- prep: 5 weight transposes + both input LNs, one dispatch ----------------
__global__ __launch_bounds__(256) void prep_kernel(
    const float* __restrict__ Wq, const float* __restrict__ Wkv,
    const float* __restrict__ Wp, const float* __restrict__ W1,
    const float* __restrict__ W2,
    __hip_bfloat16* __restrict__ oq, __hip_bfloat16* __restrict__ okv,
    __hip_bfloat16* __restrict__ op_, __hip_bfloat16* __restrict__ o1,
    __hip_bfloat16* __restrict__ o2,
    const float* __restrict__ q, const float* __restrict__ kv,
    const float* __restrict__ qg, const float* __restrict__ qb,
    const float* __restrict__ kg, const float* __restrict__ kb2,
    __hip_bfloat16* __restrict__ qn, __hip_bfloat16* __restrict__ kvn){
  const int bid = blockIdx.x;
  const int tid = threadIdx.x;
  if(bid < 6912){
    __shared__ float tile[32][33];
    const float* in; __hip_bfloat16* out; int K, N, local;
    if(bid < 576)        { in=Wq;  out=oq;  K=768;  N=768;  local=bid; }
    else if(bid < 1728)  { in=Wkv; out=okv; K=768;  N=1536; local=bid-576; }
    else if(bid < 2304)  { in=Wp;  out=op_; K=768;  N=768;  local=bid-1728; }
    else if(bid < 4608)  { in=W1;  out=o1;  K=768;  N=3072; local=bid-2304; }
    else                 { in=W2;  out=o2;  K=3072; N=768;  local=bid-4608; }
    const int nbx = N/32;
    const int n0 = (local % nbx)*32, k0 = (local / nbx)*32;
    const int tx = tid & 31, ty = tid >> 5;
#pragma unroll
    for(int i=0;i<4;i++) tile[ty+i*8][tx] = in[(size_t)(k0+ty+i*8)*N + n0+tx];
    __syncthreads();
#pragma unroll
    for(int i=0;i<4;i++) out[(size_t)(n0+ty+i*8)*K + k0+tx] = f2bf(tile[tx][ty+i*8]);
  } else {
    int row = bid - 6912;
    if(row < 4096) ln_body(q + (size_t)row*768, qg, qb, qn + (size_t)row*768, tid);
    else { row -= 4096; ln_body(kv + (size_t)row*768, kg, kb2, kvn + (size_t)row*768, tid); }
  }
}

__global__ __launch_bounds__(256) void ln_kernel(const float* __restrict__ in,
    const float* __restrict__ g, const float* __restrict__ b,
    __hip_bfloat16* __restrict__ out){
  int row = blockIdx.x, t = threadIdx.x;
  ln_body(in + (size_t)row*768, g, b, out + (size_t)row*768, t);
}

// ---------------- GEMM: gload_lds w/ pre-swizzled source, swizzled ds_read ----
// 64x64 tiles: 3-buffer depth-2 pipeline, single barrier/iter, counted vmcnt (T3/T4).
// 128x128 tiles: 2-buffer 2-phase.
// C[M][N] = A[M][K] * BT[N][K]^T.
// EPI: 0=*0.125->bf16  1=KV split: K->kbuf, V(+tem) -> vt transposed per (b,h)
//      2=+resid(f32)->f32  3=gelu->bf16  4=+resid(f32)->f32
template<int BM, int BN, int EPI>
__global__ __launch_bounds__(256) void gemm_gl(
    const __hip_bfloat16* __restrict__ A, const __hip_bfloat16* __restrict__ BT,
    const float* __restrict__ bias, int M, int N, int K,
    void* __restrict__ out, const void* __restrict__ aux0, void* __restrict__ out2){
  constexpr int WR = (BM==128 || BN==64) ? 2 : 1;   // wave rows
  constexpr int WC = 4/WR;                          // wave cols
  constexpr int MF = BM/(WR*16);
  constexpr int NF = BN/(WC*16);
  constexpr int NBUF = (BM==64 && BN==64) ? 3 : 2;
  constexpr int LPS = BM/32 + BN/32;                // loads per stage per wave
  __shared__ char sA[NBUF][BM*128];
  __shared__ char sB[NBUF][BN*128];
  const int tid = threadIdx.x;
  const int l = tid & 63, w = tid >> 6;
  const int lg = l >> 4, li = l & 15;
  const int wrow = (WR==2) ? (w>>1)*(BM/2) : 0;
  const int wcol = (WC==2) ? (w&1)*(BN/2) : w*(BN/4);
  const int bm = blockIdx.x * BM;
  const int bn = blockIdx.y * BN;
  const int arow = w*(BM/4) + (l>>3);
  const int brow = w*(BN/4) + (l>>3);
  const int scol = ((((l&7)*16) ^ ((l>>3)<<4)) >> 1);

  auto stage = [&](int buf, int kt){
    const int k0 = kt*64;
#pragma unroll
    for(int i=0;i<BM/32;i++)
      gload16(A  + (size_t)(bm+arow+i*8)*K + k0 + scol, sA[buf] + (w*(BM/4))*128 + i*1024);
#pragma unroll
    for(int i=0;i<BN/32;i++)
      gload16(BT + (size_t)(bn+brow+i*8)*K + k0 + scol, sB[buf] + (w*(BN/4))*128 + i*1024);
  };

  f32x4 acc[MF][NF] = {};
  const int nk = K >> 6;

  if constexpr(NBUF==3){
    stage(0, 0);
    stage(1, 1);
  } else {
    stage(0, 0);
    __syncthreads();
  }

  for(int kt=0; kt<nk; ++kt){
    const char *cA, *cB;
    if constexpr(NBUF==3){
      if(kt+1 < nk) asm volatile("s_waitcnt vmcnt(%0)" :: "i"(LPS) : "memory");
      else          asm volatile("s_waitcnt vmcnt(0)" ::: "memory");
      __builtin_amdgcn_s_barrier();
      if(kt+2 < nk) stage((kt+2)%3, kt+2);
      cA = sA[kt%3]; cB = sB[kt%3];
    } else {
      const int cur = kt & 1;
      if(kt+1 < nk) stage(cur^1, kt+1);
      cA = sA[cur]; cB = sB[cur];
    }
#pragma unroll
    for(int kk=0;kk<2;kk++){
      const int kb = kk*64 + lg*16;
      bf16x8 af[MF], bfr[NF];
#pragma unroll
      for(int m=0;m<MF;m++){
        int row = wrow+m*16+li;
        af[m] = *(const bf16x8*)(cA + row*128 + (kb ^ ((row&7)<<4)));
      }
#pragma unroll
      for(int n=0;n<NF;n++){
        int row = wcol+n*16+li;
        bfr[n] = *(const bf16x8*)(cB + row*128 + (kb ^ ((row&7)<<4)));
      }
#pragma unroll
      for(int m=0;m<MF;m++)
#pragma unroll
        for(int n=0;n<NF;n++)
          acc[m][n] = __builtin_amdgcn_mfma_f32_16x16x32_bf16(af[m], bfr[n], acc[m][n],0,0,0);
    }
    if constexpr(NBUF==2) __syncthreads();
  }
#pragma unroll
  for(int m=0;m<MF;m++){
#pragma unroll
    for(int n=0;n<NF;n++){
      if constexpr(EPI==1){
        const int col = bn + wcol + n*16 + li;
        const int row0 = bm + wrow + m*16 + lg*4;
        const int bb = row0 / 1344, ii = row0 % 1344;
        if(col < 768){
#pragma unroll
          for(int r=0;r<4;r++)
            ((__hip_bfloat16*)out)[(size_t)(row0+r)*768 + col] = f2bf(acc[m][n][r] + bias[col]);
        } else {
          const int c = col - 768, hh = c >> 6, d = c & 63;
          __hip_bfloat16 tmp[4];
#pragma unroll
          for(int r=0;r<4;r++){
            float v = acc[m][n][r] + bias[col];
            if(ii < 320) v += ((const float*)aux0)[((size_t)bb*320 + ii + r)*768 + c];
            tmp[r] = f2bf(v);
          }
          *(uint2*)((__hip_bfloat16*)out2 + ((size_t)(bb*12+hh)*64 + d)*1344 + ii) = *(const uint2*)tmp;
        }
      } else {
#pragma unroll
        for(int r=0;r<4;r++){
          int row = bm + wrow + m*16 + lg*4 + r;
          int col = bn + wcol + n*16 + li;
          float v = acc[m][n][r] + bias[col];
          if constexpr(EPI==0){
            ((__hip_bfloat16*)out)[(size_t)row*N + col] = f2bf(v * 0.125f);
          } else if constexpr(EPI==2){
            v += ((const float*)aux0)[(size_t)row*N + col];
            ((float*)out)[(size_t)row*N + col] = v;
          } else if constexpr(EPI==3){
            // tanh-form GELU (|dev vs exact erf-gelu| <~1e-3): guarded against exp overflow
            float u = v*(0.7978845608f + 0.0356774081f*v*v);
            float e = __expf(-2.f*fabsf(u));
            float th = (1.f - e)/(1.f + e);
            th = (u < 0.f) ? -th : th;
            ((__hip_bfloat16*)out)[(size_t)row*N + col] = f2bf(0.5f*v*(1.f+th));
          } else {
            v += ((const float*)aux0)[(size_t)row*N + col];
            ((float*)out)[(size_t)row*N + col] = v;
          }
        }
      }
    }
  }
}

// ---------------- fused attention: one block per (b, h, 64-row Q tile) ----------------
// SWAPPED QK^T: accT[m] = mfma(K_frag, Q_frag) -> S^T[kv][q=li]. Per lane: one q-column,
// softmax max fully in-lane (scalar mrun), pos via 4x float4, P written as 4x ds_write_b64
// (kv-contiguous) into the SAME [16 q][64 kv] swizzled layout -> PV read path unchanged.
// Denominator via ones-column MFMA (accL). Counted vmcnt; defer-max with per-lane vote.
__global__ __launch_bounds__(256) void attn_kernel(
    const __hip_bfloat16* __restrict__ qh,  // (B*LQ, 768), pre-scaled by 0.125
    const __hip_bfloat16* __restrict__ kb,  // (B*LKV, 768)
    const __hip_bfloat16* __restrict__ vt,  // (B*H*64, 1344)  V transposed per (b,h)
    const float* __restrict__ pos,          // (H, LQ, LKV) f32
    __hip_bfloat16* __restrict__ xo){       // (B*LQ, 768)
  __shared__ char sK[2][8192];     // [kv][d] swizzled: byte x = d*2 ^ ((kv&7)<<4)
  __shared__ char sV[2][8192];     // [d][kv] swizzled: byte x = kv*2 ^ ((d&7)<<4)
  __shared__ char sP[4][2048];     // per-wave [q][kv] swizzled (wave-private)
  const int bid = blockIdx.x;
  const int qt = bid & 15, h = (bid >> 4) % 12, b = bid / 192;
  const int q0 = qt * 64;
  const int tid = threadIdx.x;
  const int l = tid & 63, w = tid >> 6;
  const int lg = l >> 4, li = l & 15;

  const int srow = w*16 + (l>>3);
  const int soff = (((l&7)*16) ^ ((l>>3)<<4)) >> 1;
  const __hip_bfloat16* ksrc = kb + ((size_t)b*1344 + srow)*768 + h*64 + soff;
  const __hip_bfloat16* vsrc = vt + ((size_t)(b*12+h)*64 + srow)*1344 + soff;

  bf16x8 aq[2];
  {
    const char* qp = (const char*)(qh + ((size_t)(b*1024 + q0 + w*16 + li))*768 + h*64);
    aq[0] = *(const bf16x8*)(qp + lg*16);
    aq[1] = *(const bf16x8*)(qp + 64 + lg*16);
  }
  bf16x8 ones;
#pragma unroll
  for(int i=0;i<8;i++) ones[i] = (__bf16)1.0f;
  // swapped orientation: this lane owns q-column (w*16+li), kv rows lg*4+r (+16m)
  const size_t posbase = ((size_t)h*1024 + q0 + w*16 + li)*1344 + lg*4;

  f32x4 accO[4] = {};
  f32x4 accL = {};                 // accL[r] = running softmax denominator for q-row lg*4+r
  float mrun = -1e30f;             // running max for THIS lane's q-column (q=li)

  auto stage = [&](int buf, int t){
    const size_t ko = (size_t)t*64*768;
    const size_t vo = (size_t)t*64;
    gload16(ksrc + ko,          sK[buf] + w*2048);
    gload16(ksrc + ko + 8*768,  sK[buf] + w*2048 + 1024);
    gload16(vsrc + vo,          sV[buf] + w*2048);
    gload16(vsrc + vo + 8*1344, sV[buf] + w*2048 + 1024);
  };
  auto ldpos = [&](int t, f32x4 (&pr)[4]){
    const float* pp = pos + posbase + (size_t)t*64;
#pragma unroll
    for(int m=0;m<4;m++)
      pr[m] = __builtin_nontemporal_load((const f32x4*)(pp + m*16));
  };

  f32x4 pA[4], pB[4];
  ldpos(0, pA);
  stage(0, 0);
  __syncthreads();

  char* sPw = sP[w];

  auto body = [&](int t, f32x4 (&posr)[4], f32x4 (&npos)[4]){
    const int cur = t & 1;
    const bool more = (t < 20);
    // S^T = K Q^T (swapped operands; Q pre-scaled by 1/8)
    f32x4 accT[4] = {};
    __builtin_amdgcn_s_setprio(1);
#pragma unroll
    for(int kk=0; kk<2; ++kk){
      const int kbyte = kk*64 + lg*16;
#pragma unroll
      for(int m=0;m<4;m++){
        int row = m*16 + li;
        bf16x8 bkf = *(const bf16x8*)(sK[cur] + row*128 + (kbyte ^ ((row&7)<<4)));
        accT[m] = __builtin_amdgcn_mfma_f32_16x16x32_bf16(bkf, aq[kk], accT[m], 0,0,0);
      }
    }
    __builtin_amdgcn_s_setprio(0);
    // issue next tile's K/V stage, then pos loads (order pinned)
    if(more) stage(cur^1, t+1);
    asm volatile("" ::: "memory");
    if(more) ldpos(t+1, npos);

    // ---- softmax (per-lane q-column), defer-max (THR=8) with per-lane trigger vote ----
    float p[4][4];
    float mt = -1e30f;
#pragma unroll
    for(int m=0;m<4;m++)
#pragma unroll
      for(int r=0;r<4;r++){
        float s = accT[m][r] + posr[m][r];
        p[m][r] = s;
        mt = fmaxf(mt, s);
      }
    if(__any(mt > mrun + 8.f)){   // rare: full per-q max + rescale only when max drifted
      float mf = mt;
      mf = fmaxf(mf, __shfl_xor(mf, 16));
      mf = fmaxf(mf, __shfl_xor(mf, 32));
      float mnew = fmaxf(mrun, mf);
      float sf = __expf(mrun - mnew);
      mrun = mnew;
      // rescale accO/accL (orientation q=lg*4+r): fetch sf of that q from lane (0, lg*4+r)
#pragma unroll
      for(int r=0;r<4;r++){
        float sfr = __shfl(sf, lg*4 + r);
        accL[r] *= sfr;
#pragma unroll
        for(int n=0;n<4;n++) accO[n][r] *= sfr;
      }
    }
#pragma unroll
    for(int m=0;m<4;m++)
#pragma unroll
      for(int r=0;r<4;r++) p[m][r] = __expf(p[m][r]-mrun);
    // P tile write: row q=li, kv=m*16+lg*4..+4 contiguous -> 4x b64 (same layout+swizzle as read)
#pragma unroll
    for(int m=0;m<4;m++){
      __hip_bfloat16 t4[4];
#pragma unroll
      for(int r=0;r<4;r++) t4[r] = f2bf(p[m][r]);
      const int off = (m*32 + lg*8) ^ ((li&7)<<4);
      *(uint2*)(sPw + li*128 + off) = *(const uint2*)t4;
    }
    // O += P V ; denominator: accL += P * ones   (unchanged orientation)
    __builtin_amdgcn_s_setprio(1);
#pragma unroll
    for(int kk=0; kk<2; ++kk){
      const int kbyte = kk*64 + lg*16;
      bf16x8 pa = *(const bf16x8*)(sPw + li*128 + (kbyte ^ ((li&7)<<4)));
      accL = __builtin_amdgcn_mfma_f32_16x16x32_bf16(pa, ones, accL, 0,0,0);
#pragma unroll
      for(int n=0;n<4;n++){
        int d = n*16 + li;
        bf16x8 bvf = *(const bf16x8*)(sV[cur] + d*128 + (kbyte ^ ((d&7)<<4)));
        accO[n] = __builtin_amdgcn_mfma_f32_16x16x32_bf16(pa, bvf, accO[n], 0,0,0);
      }
    }
    __builtin_amdgcn_s_setprio(0);
    if(more){
      // retire exactly the 4 K/V stage loads; 4 pos loads stay in flight across the barrier
      asm volatile("s_waitcnt vmcnt(4)" ::: "memory");
      __builtin_amdgcn_s_barrier();
    }
  };

  for(int tt=0; tt<10; ++tt){
    body(2*tt,   pA, pB);
    body(2*tt+1, pB, pA);
  }
  body(20, pA, pB);

#pragma unroll
  for(int n=0;n<4;n++)
#pragma unroll
    for(int r=0;r<4;r++){
      int row = b*1024 + q0 + w*16 + lg*4 + r;
      int col = h*64 + n*16 + li;
      xo[(size_t)row*768 + col] = f2bf(accO[n][r] / accL[r]);
    }
}

extern "C" void kernel_launch(void* const* d_in, const int* in_sizes, int n_in,
                              void* d_out, int out_size, void* d_ws, size_t ws_size,
                              hipStream_t stream){
  const float* tem   = (const float*)d_in[0];
  const float* qin   = (const float*)d_in[1];
  const float* kvin  = (const float*)d_in[2];
  const float* pos   = (const float*)d_in[3];
  const float* ln1qg = (const float*)d_in[4];
  const float* ln1qb = (const float*)d_in[5];
  const float* ln1kg = (const float*)d_in[6];
  const float* ln1kb = (const float*)d_in[7];
  const float* Wq    = (const float*)d_in[8];
  const float* bq    = (const float*)d_in[9];
  const float* Wkv   = (const float*)d_in[10];
  const float* bkv   = (const float*)d_in[11];
  const float* Wp    = (const float*)d_in[12];
  const float* bp    = (const float*)d_in[13];
  const float* ln2g  = (const float*)d_in[14];
  const float* ln2b  = (const float*)d_in[15];
  const float* W1    = (const float*)d_in[16];
  const float* b1    = (const float*)d_in[17];
  const float* W2    = (const float*)d_in[18];
  const float* b2    = (const float*)d_in[19];

  char* ws = (char*)d_ws; size_t off = 0;
  auto alloc = [&](size_t n){ char* p = ws + off; off = (off + n + 255) & ~(size_t)255; return p; };
  __hip_bfloat16* WqT  = (__hip_bfloat16*)alloc((size_t)768*768*2);
  __hip_bfloat16* WkvT = (__hip_bfloat16*)alloc((size_t)1536*768*2);
  __hip_bfloat16* WpT  = (__hip_bfloat16*)alloc((size_t)768*768*2);
  __hip_bfloat16* W1T  = (__hip_bfloat16*)alloc((size_t)3072*768*2);
  __hip_bfloat16* W2T  = (__hip_bfloat16*)alloc((size_t)768*3072*2);
  __hip_bfloat16* qn   = (__hip_bfloat16*)alloc((size_t)4096*768*2);
  char* poolBase = alloc((size_t)5376*768*2*3 + (size_t)4096*768*2); // kvn,kbuf,vt,qhb pool
  __hip_bfloat16* kvn  = (__hip_bfloat16*)poolBase;
  __hip_bfloat16* kbuf = kvn  + (size_t)5376*768;
  __hip_bfloat16* vt   = kbuf + (size_t)5376*768;   // (B*H*64, 1344) = 8.25MB, written by gemm<1>
  __hip_bfloat16* qhb  = vt   + (size_t)5376*768;
  __hip_bfloat16* xat  = (__hip_bfloat16*)alloc((size_t)4096*768*2);
  float*          x1f  = (float*)alloc((size_t)4096*768*4);
  __hip_bfloat16* hln  = qn;    // qn dead after gemm<0>
  __hip_bfloat16* h1   = kvn;   // pool dead after attn

  prep_kernel<<<16384, 256, 0, stream>>>(Wq, Wkv, Wp, W1, W2, WqT, WkvT, WpT, W1T, W2T,
                                         qin, kvin, ln1qg, ln1qb, ln1kg, ln1kb, qn, kvn);

  gemm_gl<64,64,0>  <<<dim3(64, 12), 256, 0, stream>>>(qn,  WqT,  bq,  4096, 768,  768,  qhb, nullptr, nullptr);
  gemm_gl<128,128,1><<<dim3(42, 12), 256, 0, stream>>>(kvn, WkvT, bkv, 5376, 1536, 768,  kbuf, tem, vt);

  attn_kernel<<<768, 256, 0, stream>>>(qhb, kbuf, vt, pos, xat);

  gemm_gl<64,64,2>  <<<dim3(64, 12), 256, 0, stream>>>(xat, WpT,  bp,  4096, 768,  768,  x1f, qin, nullptr);
  ln_kernel<<<4096, 256, 0, stream>>>(x1f, ln2g, ln2b, hln);
  gemm_gl<128,128,3><<<dim3(32, 24), 256, 0, stream>>>(hln, W1T,  b1,  4096, 3072, 768,  h1, nullptr, nullptr);
  gemm_gl<64,64,4>  <<<dim3(64, 12), 256, 0, stream>>>(h1,  W2T,  b2,  4096, 768,  3072, (float*)d_out, x1f, nullptr);
}

// Round 18
// 221.083 us; speedup vs baseline: 1.0185x; 1.0185x over previous
//
#include <hip/hip_runtime.h>
#include <hip/hip_bf16.h>
#include <math.h>

typedef __bf16 bf16x8 __attribute__((ext_vector_type(8)));
typedef float f32x4 __attribute__((ext_vector_type(4)));

__device__ __forceinline__ __hip_bfloat16 f2bf(float v){ return __float2bfloat16(v); }

// async global->LDS, 16B per lane; LDS dest is wave-uniform base (lane i writes base+i*16),
// global source is PER-LANE (swizzled layouts via pre-swizzled source addresses).
__device__ __forceinline__ void gload16(const void* g, void* l){
  __builtin_amdgcn_global_load_lds(
      (const __attribute__((address_space(1))) void*)g,
      (__attribute__((address_space(3))) void*)l, 16, 0, 0);
}

// ---------------- LayerNorm body over C=768 ----------------
__device__ __forceinline__ void ln_body(const float* rp, const float* g, const float* b,
                                        __hip_bfloat16* op, int t){
  float x0 = rp[t], x1 = rp[t+256], x2 = rp[t+512];
  float s = x0+x1+x2, ss = x0*x0+x1*x1+x2*x2;
#pragma unroll
  for(int o=32;o>0;o>>=1){ s += __shfl_down(s,o); ss += __shfl_down(ss,o); }
  __shared__ float red[10];
  if((t&63)==0){ red[t>>6]=s; red[4+(t>>6)]=ss; }
  __syncthreads();
  if(t==0){
    float S=red[0]+red[1]+red[2]+red[3], SS=red[4]+red[5]+red[6]+red[7];
    float m=S*(1.f/768.f);
    red[8]=m; red[9]=SS*(1.f/768.f)-m*m;
  }
  __syncthreads();
  float m=red[8], r=rsqrtf(red[9]+1e-5f);
  op[t]     = f2bf((x0-m)*r*g[t]     + b[t]);
  op[t+256] = f2bf((x1-m)*r*g[t+256] + b[t+256]);
  op[t+512] = f2bf((x2-m)*r*g[t+512] + b[t+512]);
}

// ---------------- prep: 5 weight transposes + both input LNs, one dispatch ----------------
__global__ __launch_bounds__(256) void prep_kernel(
    const float* __restrict__ Wq, const float* __restrict__ Wkv,
    const float* __restrict__ Wp, const float* __restrict__ W1,
    const float* __restrict__ W2,
    __hip_bfloat16* __restrict__ oq, __hip_bfloat16* __restrict__ okv,
    __hip_bfloat16* __restrict__ op_, __hip_bfloat16* __restrict__ o1,
    __hip_bfloat16* __restrict__ o2,
    const float* __restrict__ q, const float* __restrict__ kv,
    const float* __restrict__ qg, const float* __restrict__ qb,
    const float* __restrict__ kg, const float* __restrict__ kb2,
    __hip_bfloat16* __restrict__ qn, __hip_bfloat16* __restrict__ kvn){
  const int bid = blockIdx.x;
  const int tid = threadIdx.x;
  if(bid < 6912){
    __shared__ float tile[32][33];
    const float* in; __hip_bfloat16* out; int K, N, local;
    if(bid < 576)        { in=Wq;  out=oq;  K=768;  N=768;  local=bid; }
    else if(bid < 1728)  { in=Wkv; out=okv; K=768;  N=1536; local=bid-576; }
    else if(bid < 2304)  { in=Wp;  out=op_; K=768;  N=768;  local=bid-1728; }
    else if(bid < 4608)  { in=W1;  out=o1;  K=768;  N=3072; local=bid-2304; }
    else                 { in=W2;  out=o2;  K=3072; N=768;  local=bid-4608; }
    const int nbx = N/32;
    const int n0 = (local % nbx)*32, k0 = (local / nbx)*32;
    const int tx = tid & 31, ty = tid >> 5;
#pragma unroll
    for(int i=0;i<4;i++) tile[ty+i*8][tx] = in[(size_t)(k0+ty+i*8)*N + n0+tx];
    __syncthreads();
#pragma unroll
    for(int i=0;i<4;i++) out[(size_t)(n0+ty+i*8)*K + k0+tx] = f2bf(tile[tx][ty+i*8]);
  } else {
    int row = bid - 6912;
    if(row < 4096) ln_body(q + (size_t)row*768, qg, qb, qn + (size_t)row*768, tid);
    else { row -= 4096; ln_body(kv + (size_t)row*768, kg, kb2, kvn + (size_t)row*768, tid); }
  }
}

__global__ __launch_bounds__(256) void ln_kernel(const float* __restrict__ in,
    const float* __restrict__ g, const float* __restrict__ b,
    __hip_bfloat16* __restrict__ out){
  int row = blockIdx.x, t = threadIdx.x;
  ln_body(in + (size_t)row*768, g, b, out + (size_t)row*768, t);
}

// ---------------- GEMM: gload_lds w/ pre-swizzled source, swizzled ds_read ----
// 64x64 tiles: 3-buffer depth-2 pipeline, single barrier/iter, counted vmcnt (T3/T4).
// 128x128 tiles: 2-buffer 2-phase.
// C[M][N] = A[M][K] * BT[N][K]^T.
// EPI: 0=*0.125->bf16  1=KV split: K->kbuf, V(+tem) -> vt transposed per (b,h)
//      2=+resid(f32)->f32  3=gelu->bf16  4=+resid(f32)->f32
template<int BM, int BN, int EPI>
__global__ __launch_bounds__(256) void gemm_gl(
    const __hip_bfloat16* __restrict__ A, const __hip_bfloat16* __restrict__ BT,
    const float* __restrict__ bias, int M, int N, int K,
    void* __restrict__ out, const void* __restrict__ aux0, void* __restrict__ out2){
  constexpr int WR = (BM==128 || BN==64) ? 2 : 1;   // wave rows
  constexpr int WC = 4/WR;                          // wave cols
  constexpr int MF = BM/(WR*16);
  constexpr int NF = BN/(WC*16);
  constexpr int NBUF = (BM==64 && BN==64) ? 3 : 2;
  constexpr int LPS = BM/32 + BN/32;                // loads per stage per wave
  __shared__ char sA[NBUF][BM*128];
  __shared__ char sB[NBUF][BN*128];
  const int tid = threadIdx.x;
  const int l = tid & 63, w = tid >> 6;
  const int lg = l >> 4, li = l & 15;
  const int wrow = (WR==2) ? (w>>1)*(BM/2) : 0;
  const int wcol = (WC==2) ? (w&1)*(BN/2) : w*(BN/4);
  const int bm = blockIdx.x * BM;
  const int bn = blockIdx.y * BN;
  const int arow = w*(BM/4) + (l>>3);
  const int brow = w*(BN/4) + (l>>3);
  const int scol = ((((l&7)*16) ^ ((l>>3)<<4)) >> 1);

  auto stage = [&](int buf, int kt){
    const int k0 = kt*64;
#pragma unroll
    for(int i=0;i<BM/32;i++)
      gload16(A  + (size_t)(bm+arow+i*8)*K + k0 + scol, sA[buf] + (w*(BM/4))*128 + i*1024);
#pragma unroll
    for(int i=0;i<BN/32;i++)
      gload16(BT + (size_t)(bn+brow+i*8)*K + k0 + scol, sB[buf] + (w*(BN/4))*128 + i*1024);
  };

  f32x4 acc[MF][NF] = {};
  const int nk = K >> 6;

  if constexpr(NBUF==3){
    stage(0, 0);
    stage(1, 1);
  } else {
    stage(0, 0);
    __syncthreads();
  }

  for(int kt=0; kt<nk; ++kt){
    const char *cA, *cB;
    if constexpr(NBUF==3){
      if(kt+1 < nk) asm volatile("s_waitcnt vmcnt(%0)" :: "i"(LPS) : "memory");
      else          asm volatile("s_waitcnt vmcnt(0)" ::: "memory");
      __builtin_amdgcn_s_barrier();
      if(kt+2 < nk) stage((kt+2)%3, kt+2);
      cA = sA[kt%3]; cB = sB[kt%3];
    } else {
      const int cur = kt & 1;
      if(kt+1 < nk) stage(cur^1, kt+1);
      cA = sA[cur]; cB = sB[cur];
    }
#pragma unroll
    for(int kk=0;kk<2;kk++){
      const int kb = kk*64 + lg*16;
      bf16x8 af[MF], bfr[NF];
#pragma unroll
      for(int m=0;m<MF;m++){
        int row = wrow+m*16+li;
        af[m] = *(const bf16x8*)(cA + row*128 + (kb ^ ((row&7)<<4)));
      }
#pragma unroll
      for(int n=0;n<NF;n++){
        int row = wcol+n*16+li;
        bfr[n] = *(const bf16x8*)(cB + row*128 + (kb ^ ((row&7)<<4)));
      }
#pragma unroll
      for(int m=0;m<MF;m++)
#pragma unroll
        for(int n=0;n<NF;n++)
          acc[m][n] = __builtin_amdgcn_mfma_f32_16x16x32_bf16(af[m], bfr[n], acc[m][n],0,0,0);
    }
    if constexpr(NBUF==2) __syncthreads();
  }
#pragma unroll
  for(int m=0;m<MF;m++){
#pragma unroll
    for(int n=0;n<NF;n++){
      if constexpr(EPI==1){
        const int col = bn + wcol + n*16 + li;
        const int row0 = bm + wrow + m*16 + lg*4;
        const int bb = row0 / 1344, ii = row0 % 1344;
        if(col < 768){
#pragma unroll
          for(int r=0;r<4;r++)
            ((__hip_bfloat16*)out)[(size_t)(row0+r)*768 + col] = f2bf(acc[m][n][r] + bias[col]);
        } else {
          const int c = col - 768, hh = c >> 6, d = c & 63;
          __hip_bfloat16 tmp[4];
#pragma unroll
          for(int r=0;r<4;r++){
            float v = acc[m][n][r] + bias[col];
            if(ii < 320) v += ((const float*)aux0)[((size_t)bb*320 + ii + r)*768 + c];
            tmp[r] = f2bf(v);
          }
          *(uint2*)((__hip_bfloat16*)out2 + ((size_t)(bb*12+hh)*64 + d)*1344 + ii) = *(const uint2*)tmp;
        }
      } else {
#pragma unroll
        for(int r=0;r<4;r++){
          int row = bm + wrow + m*16 + lg*4 + r;
          int col = bn + wcol + n*16 + li;
          float v = acc[m][n][r] + bias[col];
          if constexpr(EPI==0){
            ((__hip_bfloat16*)out)[(size_t)row*N + col] = f2bf(v * 0.125f);
          } else if constexpr(EPI==2){
            v += ((const float*)aux0)[(size_t)row*N + col];
            ((float*)out)[(size_t)row*N + col] = v;
          } else if constexpr(EPI==3){
            // tanh-form GELU (|dev vs exact erf-gelu| <~1e-3): guarded against exp overflow
            float u = v*(0.7978845608f + 0.0356774081f*v*v);
            float e = __expf(-2.f*fabsf(u));
            float th = (1.f - e)/(1.f + e);
            th = (u < 0.f) ? -th : th;
            ((__hip_bfloat16*)out)[(size_t)row*N + col] = f2bf(0.5f*v*(1.f+th));
          } else {
            v += ((const float*)aux0)[(size_t)row*N + col];
            ((float*)out)[(size_t)row*N + col] = v;
          }
        }
      }
    }
  }
}

// ---------------- fused attention (r13/r16-exact): one block per (b, h, 64-row Q tile) ----------------
// K/V via gload_lds w/ inverse-swizzled sources; counted vmcnt; defer-max softmax with
// PER-LANE trigger vote (shuffle max-reduce only inside the rare rescale branch);
// row-sum denominator via ones-column MFMA (accL).
__global__ __launch_bounds__(256) void attn_kernel(
    const __hip_bfloat16* __restrict__ qh,  // (B*LQ, 768), pre-scaled by 0.125
    const __hip_bfloat16* __restrict__ kb,  // (B*LKV, 768)
    const __hip_bfloat16* __restrict__ vt,  // (B*H*64, 1344)  V transposed per (b,h)
    const float* __restrict__ pos,          // (H, LQ, LKV) f32
    __hip_bfloat16* __restrict__ xo){       // (B*LQ, 768)
  __shared__ char sK[2][8192];     // [kv][d] swizzled: byte x = d*2 ^ ((kv&7)<<4)
  __shared__ char sV[2][8192];     // [d][kv] swizzled: byte x = kv*2 ^ ((d&7)<<4)
  __shared__ char sP[4][2048];     // per-wave [q][kv] swizzled (wave-private)
  const int bid = blockIdx.x;
  const int qt = bid & 15, h = (bid >> 4) % 12, b = bid / 192;
  const int q0 = qt * 64;
  const int tid = threadIdx.x;
  const int l = tid & 63, w = tid >> 6;
  const int lg = l >> 4, li = l & 15;

  const int srow = w*16 + (l>>3);
  const int soff = (((l&7)*16) ^ ((l>>3)<<4)) >> 1;
  const __hip_bfloat16* ksrc = kb + ((size_t)b*1344 + srow)*768 + h*64 + soff;
  const __hip_bfloat16* vsrc = vt + ((size_t)(b*12+h)*64 + srow)*1344 + soff;

  bf16x8 aq[2];
  {
    const char* qp = (const char*)(qh + ((size_t)(b*1024 + q0 + w*16 + li))*768 + h*64);
    aq[0] = *(const bf16x8*)(qp + lg*16);
    aq[1] = *(const bf16x8*)(qp + 64 + lg*16);
  }
  bf16x8 ones;
#pragma unroll
  for(int i=0;i<8;i++) ones[i] = (__bf16)1.0f;
  const size_t posbase = ((size_t)h*1024 + q0 + w*16 + lg*4)*1344 + li;

  f32x4 accO[4] = {};
  f32x4 accL = {};                 // accL[r] = running softmax denominator for q-row lg*4+r
  float mrun[4];
#pragma unroll
  for(int r=0;r<4;r++) mrun[r] = -1e30f;

  auto stage = [&](int buf, int t){
    const size_t ko = (size_t)t*64*768;
    const size_t vo = (size_t)t*64;
    gload16(ksrc + ko,          sK[buf] + w*2048);
    gload16(ksrc + ko + 8*768,  sK[buf] + w*2048 + 1024);
    gload16(vsrc + vo,          sV[buf] + w*2048);
    gload16(vsrc + vo + 8*1344, sV[buf] + w*2048 + 1024);
  };
  auto ldpos = [&](int t, float (&pr)[4][4]){
    const float* pp = pos + posbase + (size_t)t*64;
#pragma unroll
    for(int n=0;n<4;n++)
#pragma unroll
      for(int r=0;r<4;r++)
        pr[n][r] = __builtin_nontemporal_load(pp + (size_t)r*1344 + n*16);
  };

  float pA[4][4], pB[4][4];
  ldpos(0, pA);
  stage(0, 0);
  __syncthreads();

  char* sPw = sP[w];

  auto body = [&](int t, float (&posr)[4][4], float (&npos)[4][4]){
    const int cur = t & 1;
    const bool more = (t < 20);
    // S = Q K^T (Q pre-scaled by 1/8)
    f32x4 accS[4] = {};
    __builtin_amdgcn_s_setprio(1);
#pragma unroll
    for(int kk=0; kk<2; ++kk){
      const int kbyte = kk*64 + lg*16;
#pragma unroll
      for(int n=0;n<4;n++){
        int row = n*16 + li;
        bf16x8 bkf = *(const bf16x8*)(sK[cur] + row*128 + (kbyte ^ ((row&7)<<4)));
        accS[n] = __builtin_amdgcn_mfma_f32_16x16x32_bf16(aq[kk], bkf, accS[n], 0,0,0);
      }
    }
    __builtin_amdgcn_s_setprio(0);
    // issue next tile's K/V stage, then pos loads (order pinned)
    if(more) stage(cur^1, t+1);
    asm volatile("" ::: "memory");
    if(more) ldpos(t+1, npos);

    // ---- softmax, defer-max (THR=8) with per-lane trigger vote ----
    float p[4][4], mt[4];
#pragma unroll
    for(int r=0;r<4;r++) mt[r] = -1e30f;
#pragma unroll
    for(int n=0;n<4;n++)
#pragma unroll
      for(int r=0;r<4;r++){
        float s = accS[n][r] + posr[n][r];
        p[n][r] = s;
        mt[r] = fmaxf(mt[r], s);
      }
    bool need = false;
#pragma unroll
    for(int r=0;r<4;r++) need |= (mt[r] > mrun[r] + 8.f);
    if(__any(need)){   // rare: full row-reduce + rescale only when max actually drifted
#pragma unroll
      for(int r=0;r<4;r++){
#pragma unroll
        for(int o=1;o<16;o<<=1) mt[r] = fmaxf(mt[r], __shfl_xor(mt[r], o));
        float mnew = fmaxf(mrun[r], mt[r]);
        float sf = __expf(mrun[r]-mnew);
        mrun[r] = mnew;
        accL[r] *= sf;
#pragma unroll
        for(int n=0;n<4;n++) accO[n][r] *= sf;
      }
    }
#pragma unroll
    for(int n=0;n<4;n++)
#pragma unroll
      for(int r=0;r<4;r++) p[n][r] = __expf(p[n][r]-mrun[r]);
    // P tile (wave-private)
#pragma unroll
    for(int n=0;n<4;n++)
#pragma unroll
      for(int r=0;r<4;r++){
        int qi = lg*4 + r, kj = n*16 + li;
        *(__hip_bfloat16*)(sPw + qi*128 + ((kj*2) ^ ((qi&7)<<4))) = f2bf(p[n][r]);
      }
    // O += P V ; denominator: accL += P * ones
    __builtin_amdgcn_s_setprio(1);
#pragma unroll
    for(int kk=0; kk<2; ++kk){
      const int kbyte = kk*64 + lg*16;
      bf16x8 pa = *(const bf16x8*)(sPw + li*128 + (kbyte ^ ((li&7)<<4)));
      accL = __builtin_amdgcn_mfma_f32_16x16x32_bf16(pa, ones, accL, 0,0,0);
#pragma unroll
      for(int n=0;n<4;n++){
        int d = n*16 + li;
        bf16x8 bvf = *(const bf16x8*)(sV[cur] + d*128 + (kbyte ^ ((d&7)<<4)));
        accO[n] = __builtin_amdgcn_mfma_f32_16x16x32_bf16(pa, bvf, accO[n], 0,0,0);
      }
    }
    __builtin_amdgcn_s_setprio(0);
    if(more){
      // retire exactly the 4 K/V stage loads; 16 pos loads stay in flight across the barrier
      asm volatile("s_waitcnt vmcnt(16)" ::: "memory");
      __builtin_amdgcn_s_barrier();
    }
  };

  for(int tt=0; tt<10; ++tt){
    body(2*tt,   pA, pB);
    body(2*tt+1, pB, pA);
  }
  body(20, pA, pB);

#pragma unroll
  for(int n=0;n<4;n++)
#pragma unroll
    for(int r=0;r<4;r++){
      int row = b*1024 + q0 + w*16 + lg*4 + r;
      int col = h*64 + n*16 + li;
      xo[(size_t)row*768 + col] = f2bf(accO[n][r] / accL[r]);
    }
}

extern "C" void kernel_launch(void* const* d_in, const int* in_sizes, int n_in,
                              void* d_out, int out_size, void* d_ws, size_t ws_size,
                              hipStream_t stream){
  const float* tem   = (const float*)d_in[0];
  const float* qin   = (const float*)d_in[1];
  const float* kvin  = (const float*)d_in[2];
  const float* pos   = (const float*)d_in[3];
  const float* ln1qg = (const float*)d_in[4];
  const float* ln1qb = (const float*)d_in[5];
  const float* ln1kg = (const float*)d_in[6];
  const float* ln1kb = (const float*)d_in[7];
  const float* Wq    = (const float*)d_in[8];
  const float* bq    = (const float*)d_in[9];
  const float* Wkv   = (const float*)d_in[10];
  const float* bkv   = (const float*)d_in[11];
  const float* Wp    = (const float*)d_in[12];
  const float* bp    = (const float*)d_in[13];
  const float* ln2g  = (const float*)d_in[14];
  const float* ln2b  = (const float*)d_in[15];
  const float* W1    = (const float*)d_in[16];
  const float* b1    = (const float*)d_in[17];
  const float* W2    = (const float*)d_in[18];
  const float* b2    = (const float*)d_in[19];

  char* ws = (char*)d_ws; size_t off = 0;
  auto alloc = [&](size_t n){ char* p = ws + off; off = (off + n + 255) & ~(size_t)255; return p; };
  __hip_bfloat16* WqT  = (__hip_bfloat16*)alloc((size_t)768*768*2);
  __hip_bfloat16* WkvT = (__hip_bfloat16*)alloc((size_t)1536*768*2);
  __hip_bfloat16* WpT  = (__hip_bfloat16*)alloc((size_t)768*768*2);
  __hip_bfloat16* W1T  = (__hip_bfloat16*)alloc((size_t)3072*768*2);
  __hip_bfloat16* W2T  = (__hip_bfloat16*)alloc((size_t)768*3072*2);
  __hip_bfloat16* qn   = (__hip_bfloat16*)alloc((size_t)4096*768*2);
  char* poolBase = alloc((size_t)5376*768*2*3 + (size_t)4096*768*2); // kvn,kbuf,vt,qhb pool
  __hip_bfloat16* kvn  = (__hip_bfloat16*)poolBase;
  __hip_bfloat16* kbuf = kvn  + (size_t)5376*768;
  __hip_bfloat16* vt   = kbuf + (size_t)5376*768;   // (B*H*64, 1344) = 8.25MB, written by gemm<1>
  __hip_bfloat16* qhb  = vt   + (size_t)5376*768;
  __hip_bfloat16* xat  = (__hip_bfloat16*)alloc((size_t)4096*768*2);
  float*          x1f  = (float*)alloc((size_t)4096*768*4);
  __hip_bfloat16* hln  = qn;    // qn dead after gemm<0>
  __hip_bfloat16* h1   = kvn;   // pool dead after attn

  prep_kernel<<<16384, 256, 0, stream>>>(Wq, Wkv, Wp, W1, W2, WqT, WkvT, WpT, W1T, W2T,
                                         qin, kvin, ln1qg, ln1qb, ln1kg, ln1kb, qn, kvn);

  gemm_gl<64,64,0>  <<<dim3(64, 12), 256, 0, stream>>>(qn,  WqT,  bq,  4096, 768,  768,  qhb, nullptr, nullptr);
  gemm_gl<128,128,1><<<dim3(42, 12), 256, 0, stream>>>(kvn, WkvT, bkv, 5376, 1536, 768,  kbuf, tem, vt);

  attn_kernel<<<768, 256, 0, stream>>>(qhb, kbuf, vt, pos, xat);

  gemm_gl<64,64,2>  <<<dim3(64, 12), 256, 0, stream>>>(xat, WpT,  bp,  4096, 768,  768,  x1f, qin, nullptr);
  ln_kernel<<<4096, 256, 0, stream>>>(x1f, ln2g, ln2b, hln);
  gemm_gl<128,128,3><<<dim3(32, 24), 256, 0, stream>>>(hln, W1T,  b1,  4096, 3072, 768,  h1, nullptr, nullptr);
  gemm_gl<64,64,4>  <<<dim3(64, 12), 256, 0, stream>>>(h1,  W2T,  b2,  4096, 768,  3072, (float*)d_out, x1f, nullptr);
}

// Round 19
// 220.851 us; speedup vs baseline: 1.0196x; 1.0010x over previous
//
#include <hip/hip_runtime.h>
#include <hip/hip_bf16.h>
#include <math.h>

typedef __bf16 bf16x8 __attribute__((ext_vector_type(8)));
typedef float f32x4 __attribute__((ext_vector_type(4)));

__device__ __forceinline__ __hip_bfloat16 f2bf(float v){ return __float2bfloat16(v); }

// async global->LDS, 16B per lane; LDS dest is wave-uniform base (lane i writes base+i*16),
// global source is PER-LANE (swizzled layouts via pre-swizzled source addresses).
__device__ __forceinline__ void gload16(const void* g, void* l){
  __builtin_amdgcn_global_load_lds(
      (const __attribute__((address_space(1))) void*)g,
      (__attribute__((address_space(3))) void*)l, 16, 0, 0);
}

// ---------------- LayerNorm body over C=768 ----------------
__device__ __forceinline__ void ln_body(const float* rp, const float* g, const float* b,
                                        __hip_bfloat16* op, int t){
  float x0 = rp[t], x1 = rp[t+256], x2 = rp[t+512];
  float s = x0+x1+x2, ss = x0*x0+x1*x1+x2*x2;
#pragma unroll
  for(int o=32;o>0;o>>=1){ s += __shfl_down(s,o); ss += __shfl_down(ss,o); }
  __shared__ float red[10];
  if((t&63)==0){ red[t>>6]=s; red[4+(t>>6)]=ss; }
  __syncthreads();
  if(t==0){
    float S=red[0]+red[1]+red[2]+red[3], SS=red[4]+red[5]+red[6]+red[7];
    float m=S*(1.f/768.f);
    red[8]=m; red[9]=SS*(1.f/768.f)-m*m;
  }
  __syncthreads();
  float m=red[8], r=rsqrtf(red[9]+1e-5f);
  op[t]     = f2bf((x0-m)*r*g[t]     + b[t]);
  op[t+256] = f2bf((x1-m)*r*g[t+256] + b[t+256]);
  op[t+512] = f2bf((x2-m)*r*g[t+512] + b[t+512]);
}

// ---------------- prep: 5 weight transposes + both input LNs, one dispatch ----------------
__global__ __launch_bounds__(256) void prep_kernel(
    const float* __restrict__ Wq, const float* __restrict__ Wkv,
    const float* __restrict__ Wp, const float* __restrict__ W1,
    const float* __restrict__ W2,
    __hip_bfloat16* __restrict__ oq, __hip_bfloat16* __restrict__ okv,
    __hip_bfloat16* __restrict__ op_, __hip_bfloat16* __restrict__ o1,
    __hip_bfloat16* __restrict__ o2,
    const float* __restrict__ q, const float* __restrict__ kv,
    const float* __restrict__ qg, const float* __restrict__ qb,
    const float* __restrict__ kg, const float* __restrict__ kb2,
    __hip_bfloat16* __restrict__ qn, __hip_bfloat16* __restrict__ kvn){
  const int bid = blockIdx.x;
  const int tid = threadIdx.x;
  if(bid < 6912){
    __shared__ float tile[32][33];
    const float* in; __hip_bfloat16* out; int K, N, local;
    if(bid < 576)        { in=Wq;  out=oq;  K=768;  N=768;  local=bid; }
    else if(bid < 1728)  { in=Wkv; out=okv; K=768;  N=1536; local=bid-576; }
    else if(bid < 2304)  { in=Wp;  out=op_; K=768;  N=768;  local=bid-1728; }
    else if(bid < 4608)  { in=W1;  out=o1;  K=768;  N=3072; local=bid-2304; }
    else                 { in=W2;  out=o2;  K=3072; N=768;  local=bid-4608; }
    const int nbx = N/32;
    const int n0 = (local % nbx)*32, k0 = (local / nbx)*32;
    const int tx = tid & 31, ty = tid >> 5;
#pragma unroll
    for(int i=0;i<4;i++) tile[ty+i*8][tx] = in[(size_t)(k0+ty+i*8)*N + n0+tx];
    __syncthreads();
#pragma unroll
    for(int i=0;i<4;i++) out[(size_t)(n0+ty+i*8)*K + k0+tx] = f2bf(tile[tx][ty+i*8]);
  } else {
    int row = bid - 6912;
    if(row < 4096) ln_body(q + (size_t)row*768, qg, qb, qn + (size_t)row*768, tid);
    else { row -= 4096; ln_body(kv + (size_t)row*768, kg, kb2, kvn + (size_t)row*768, tid); }
  }
}

__global__ __launch_bounds__(256) void ln_kernel(const float* __restrict__ in,
    const float* __restrict__ g, const float* __restrict__ b,
    __hip_bfloat16* __restrict__ out){
  int row = blockIdx.x, t = threadIdx.x;
  ln_body(in + (size_t)row*768, g, b, out + (size_t)row*768, t);
}

// ---------------- GEMM: gload_lds w/ pre-swizzled source, swizzled ds_read ----
// 64x64 tiles: 3-buffer depth-2 pipeline, single barrier/iter, counted vmcnt (T3/T4).
// 128x128 tiles: 2-buffer 2-phase.
// C[M][N] = A[M][K] * BT[N][K]^T.
// EPI: 0=*0.125->bf16  1=KV split: K->kbuf, V(+tem) -> vt transposed per (b,h)
//      2=+resid(f32)->f32  3=gelu->bf16  4=+resid(f32)->f32
template<int BM, int BN, int EPI>
__global__ __launch_bounds__(256) void gemm_gl(
    const __hip_bfloat16* __restrict__ A, const __hip_bfloat16* __restrict__ BT,
    const float* __restrict__ bias, int M, int N, int K,
    void* __restrict__ out, const void* __restrict__ aux0, void* __restrict__ out2){
  constexpr int WR = (BM==128 || BN==64) ? 2 : 1;   // wave rows
  constexpr int WC = 4/WR;                          // wave cols
  constexpr int MF = BM/(WR*16);
  constexpr int NF = BN/(WC*16);
  constexpr int NBUF = (BM==64 && BN==64) ? 3 : 2;
  constexpr int LPS = BM/32 + BN/32;                // loads per stage per wave
  __shared__ char sA[NBUF][BM*128];
  __shared__ char sB[NBUF][BN*128];
  const int tid = threadIdx.x;
  const int l = tid & 63, w = tid >> 6;
  const int lg = l >> 4, li = l & 15;
  const int wrow = (WR==2) ? (w>>1)*(BM/2) : 0;
  const int wcol = (WC==2) ? (w&1)*(BN/2) : w*(BN/4);
  const int bm = blockIdx.x * BM;
  const int bn = blockIdx.y * BN;
  const int arow = w*(BM/4) + (l>>3);
  const int brow = w*(BN/4) + (l>>3);
  const int scol = ((((l&7)*16) ^ ((l>>3)<<4)) >> 1);

  auto stage = [&](int buf, int kt){
    const int k0 = kt*64;
#pragma unroll
    for(int i=0;i<BM/32;i++)
      gload16(A  + (size_t)(bm+arow+i*8)*K + k0 + scol, sA[buf] + (w*(BM/4))*128 + i*1024);
#pragma unroll
    for(int i=0;i<BN/32;i++)
      gload16(BT + (size_t)(bn+brow+i*8)*K + k0 + scol, sB[buf] + (w*(BN/4))*128 + i*1024);
  };

  f32x4 acc[MF][NF] = {};
  const int nk = K >> 6;

  if constexpr(NBUF==3){
    stage(0, 0);
    stage(1, 1);
  } else {
    stage(0, 0);
    __syncthreads();
  }

  for(int kt=0; kt<nk; ++kt){
    const char *cA, *cB;
    if constexpr(NBUF==3){
      if(kt+1 < nk) asm volatile("s_waitcnt vmcnt(%0)" :: "i"(LPS) : "memory");
      else          asm volatile("s_waitcnt vmcnt(0)" ::: "memory");
      __builtin_amdgcn_s_barrier();
      if(kt+2 < nk) stage((kt+2)%3, kt+2);
      cA = sA[kt%3]; cB = sB[kt%3];
    } else {
      const int cur = kt & 1;
      if(kt+1 < nk) stage(cur^1, kt+1);
      cA = sA[cur]; cB = sB[cur];
    }
#pragma unroll
    for(int kk=0;kk<2;kk++){
      const int kb = kk*64 + lg*16;
      bf16x8 af[MF], bfr[NF];
#pragma unroll
      for(int m=0;m<MF;m++){
        int row = wrow+m*16+li;
        af[m] = *(const bf16x8*)(cA + row*128 + (kb ^ ((row&7)<<4)));
      }
#pragma unroll
      for(int n=0;n<NF;n++){
        int row = wcol+n*16+li;
        bfr[n] = *(const bf16x8*)(cB + row*128 + (kb ^ ((row&7)<<4)));
      }
#pragma unroll
      for(int m=0;m<MF;m++)
#pragma unroll
        for(int n=0;n<NF;n++)
          acc[m][n] = __builtin_amdgcn_mfma_f32_16x16x32_bf16(af[m], bfr[n], acc[m][n],0,0,0);
    }
    if constexpr(NBUF==2) __syncthreads();
  }
#pragma unroll
  for(int m=0;m<MF;m++){
#pragma unroll
    for(int n=0;n<NF;n++){
      if constexpr(EPI==1){
        const int col = bn + wcol + n*16 + li;
        const int row0 = bm + wrow + m*16 + lg*4;
        const int bb = row0 / 1344, ii = row0 % 1344;
        if(col < 768){
#pragma unroll
          for(int r=0;r<4;r++)
            ((__hip_bfloat16*)out)[(size_t)(row0+r)*768 + col] = f2bf(acc[m][n][r] + bias[col]);
        } else {
          const int c = col - 768, hh = c >> 6, d = c & 63;
          __hip_bfloat16 tmp[4];
#pragma unroll
          for(int r=0;r<4;r++){
            float v = acc[m][n][r] + bias[col];
            if(ii < 320) v += ((const float*)aux0)[((size_t)bb*320 + ii + r)*768 + c];
            tmp[r] = f2bf(v);
          }
          *(uint2*)((__hip_bfloat16*)out2 + ((size_t)(bb*12+hh)*64 + d)*1344 + ii) = *(const uint2*)tmp;
        }
      } else {
#pragma unroll
        for(int r=0;r<4;r++){
          int row = bm + wrow + m*16 + lg*4 + r;
          int col = bn + wcol + n*16 + li;
          float v = acc[m][n][r] + bias[col];
          if constexpr(EPI==0){
            ((__hip_bfloat16*)out)[(size_t)row*N + col] = f2bf(v * 0.125f);
          } else if constexpr(EPI==2){
            v += ((const float*)aux0)[(size_t)row*N + col];
            ((float*)out)[(size_t)row*N + col] = v;
          } else if constexpr(EPI==3){
            // tanh-form GELU (|dev vs exact erf-gelu| <~1e-3): guarded against exp overflow
            float u = v*(0.7978845608f + 0.0356774081f*v*v);
            float e = __expf(-2.f*fabsf(u));
            float th = (1.f - e)/(1.f + e);
            th = (u < 0.f) ? -th : th;
            ((__hip_bfloat16*)out)[(size_t)row*N + col] = f2bf(0.5f*v*(1.f+th));
          } else {
            v += ((const float*)aux0)[(size_t)row*N + col];
            ((float*)out)[(size_t)row*N + col] = v;
          }
        }
      }
    }
  }
}

// ---------------- fused attention (r13/r16-exact): one block per (b, h, 64-row Q tile) ----------------
// K/V via gload_lds w/ inverse-swizzled sources; counted vmcnt; defer-max softmax with
// PER-LANE trigger vote (shuffle max-reduce only inside the rare rescale branch);
// row-sum denominator via ones-column MFMA (accL).
__global__ __launch_bounds__(256) void attn_kernel(
    const __hip_bfloat16* __restrict__ qh,  // (B*LQ, 768), pre-scaled by 0.125
    const __hip_bfloat16* __restrict__ kb,  // (B*LKV, 768)
    const __hip_bfloat16* __restrict__ vt,  // (B*H*64, 1344)  V transposed per (b,h)
    const float* __restrict__ pos,          // (H, LQ, LKV) f32
    __hip_bfloat16* __restrict__ xo){       // (B*LQ, 768)
  __shared__ char sK[2][8192];     // [kv][d] swizzled: byte x = d*2 ^ ((kv&7)<<4)
  __shared__ char sV[2][8192];     // [d][kv] swizzled: byte x = kv*2 ^ ((d&7)<<4)
  __shared__ char sP[4][2048];     // per-wave [q][kv] swizzled (wave-private)
  const int bid = blockIdx.x;
  const int qt = bid & 15, h = (bid >> 4) % 12, b = bid / 192;
  const int q0 = qt * 64;
  const int tid = threadIdx.x;
  const int l = tid & 63, w = tid >> 6;
  const int lg = l >> 4, li = l & 15;

  const int srow = w*16 + (l>>3);
  const int soff = (((l&7)*16) ^ ((l>>3)<<4)) >> 1;
  const __hip_bfloat16* ksrc = kb + ((size_t)b*1344 + srow)*768 + h*64 + soff;
  const __hip_bfloat16* vsrc = vt + ((size_t)(b*12+h)*64 + srow)*1344 + soff;

  bf16x8 aq[2];
  {
    const char* qp = (const char*)(qh + ((size_t)(b*1024 + q0 + w*16 + li))*768 + h*64);
    aq[0] = *(const bf16x8*)(qp + lg*16);
    aq[1] = *(const bf16x8*)(qp + 64 + lg*16);
  }
  bf16x8 ones;
#pragma unroll
  for(int i=0;i<8;i++) ones[i] = (__bf16)1.0f;
  const size_t posbase = ((size_t)h*1024 + q0 + w*16 + lg*4)*1344 + li;

  f32x4 accO[4] = {};
  f32x4 accL = {};                 // accL[r] = running softmax denominator for q-row lg*4+r
  float mrun[4];
#pragma unroll
  for(int r=0;r<4;r++) mrun[r] = -1e30f;

  auto stage = [&](int buf, int t){
    const size_t ko = (size_t)t*64*768;
    const size_t vo = (size_t)t*64;
    gload16(ksrc + ko,          sK[buf] + w*2048);
    gload16(ksrc + ko + 8*768,  sK[buf] + w*2048 + 1024);
    gload16(vsrc + vo,          sV[buf] + w*2048);
    gload16(vsrc + vo + 8*1344, sV[buf] + w*2048 + 1024);
  };
  auto ldpos = [&](int t, float (&pr)[4][4]){
    const float* pp = pos + posbase + (size_t)t*64;
#pragma unroll
    for(int n=0;n<4;n++)
#pragma unroll
      for(int r=0;r<4;r++)
        pr[n][r] = __builtin_nontemporal_load(pp + (size_t)r*1344 + n*16);
  };

  float pA[4][4], pB[4][4];
  ldpos(0, pA);
  stage(0, 0);
  __syncthreads();

  char* sPw = sP[w];

  auto body = [&](int t, float (&posr)[4][4], float (&npos)[4][4]){
    const int cur = t & 1;
    const bool more = (t < 20);
    // S = Q K^T (Q pre-scaled by 1/8)
    f32x4 accS[4] = {};
    __builtin_amdgcn_s_setprio(1);
#pragma unroll
    for(int kk=0; kk<2; ++kk){
      const int kbyte = kk*64 + lg*16;
#pragma unroll
      for(int n=0;n<4;n++){
        int row = n*16 + li;
        bf16x8 bkf = *(const bf16x8*)(sK[cur] + row*128 + (kbyte ^ ((row&7)<<4)));
        accS[n] = __builtin_amdgcn_mfma_f32_16x16x32_bf16(aq[kk], bkf, accS[n], 0,0,0);
      }
    }
    __builtin_amdgcn_s_setprio(0);
    // issue next tile's K/V stage, then pos loads (order pinned)
    if(more) stage(cur^1, t+1);
    asm volatile("" ::: "memory");
    if(more) ldpos(t+1, npos);

    // ---- softmax, defer-max (THR=8) with per-lane trigger vote ----
    float p[4][4], mt[4];
#pragma unroll
    for(int r=0;r<4;r++) mt[r] = -1e30f;
#pragma unroll
    for(int n=0;n<4;n++)
#pragma unroll
      for(int r=0;r<4;r++){
        float s = accS[n][r] + posr[n][r];
        p[n][r] = s;
        mt[r] = fmaxf(mt[r], s);
      }
    bool need = false;
#pragma unroll
    for(int r=0;r<4;r++) need |= (mt[r] > mrun[r] + 8.f);
    if(__any(need)){   // rare: full row-reduce + rescale only when max actually drifted
#pragma unroll
      for(int r=0;r<4;r++){
#pragma unroll
        for(int o=1;o<16;o<<=1) mt[r] = fmaxf(mt[r], __shfl_xor(mt[r], o));
        float mnew = fmaxf(mrun[r], mt[r]);
        float sf = __expf(mrun[r]-mnew);
        mrun[r] = mnew;
        accL[r] *= sf;
#pragma unroll
        for(int n=0;n<4;n++) accO[n][r] *= sf;
      }
    }
#pragma unroll
    for(int n=0;n<4;n++)
#pragma unroll
      for(int r=0;r<4;r++) p[n][r] = __expf(p[n][r]-mrun[r]);
    // P tile (wave-private)
#pragma unroll
    for(int n=0;n<4;n++)
#pragma unroll
      for(int r=0;r<4;r++){
        int qi = lg*4 + r, kj = n*16 + li;
        *(__hip_bfloat16*)(sPw + qi*128 + ((kj*2) ^ ((qi&7)<<4))) = f2bf(p[n][r]);
      }
    // O += P V ; denominator: accL += P * ones
    __builtin_amdgcn_s_setprio(1);
#pragma unroll
    for(int kk=0; kk<2; ++kk){
      const int kbyte = kk*64 + lg*16;
      bf16x8 pa = *(const bf16x8*)(sPw + li*128 + (kbyte ^ ((li&7)<<4)));
      accL = __builtin_amdgcn_mfma_f32_16x16x32_bf16(pa, ones, accL, 0,0,0);
#pragma unroll
      for(int n=0;n<4;n++){
        int d = n*16 + li;
        bf16x8 bvf = *(const bf16x8*)(sV[cur] + d*128 + (kbyte ^ ((d&7)<<4)));
        accO[n] = __builtin_amdgcn_mfma_f32_16x16x32_bf16(pa, bvf, accO[n], 0,0,0);
      }
    }
    __builtin_amdgcn_s_setprio(0);
    if(more){
      // retire exactly the 4 K/V stage loads; 16 pos loads stay in flight across the barrier
      asm volatile("s_waitcnt vmcnt(16)" ::: "memory");
      __builtin_amdgcn_s_barrier();
    }
  };

  for(int tt=0; tt<10; ++tt){
    body(2*tt,   pA, pB);
    body(2*tt+1, pB, pA);
  }
  body(20, pA, pB);

#pragma unroll
  for(int n=0;n<4;n++)
#pragma unroll
    for(int r=0;r<4;r++){
      int row = b*1024 + q0 + w*16 + lg*4 + r;
      int col = h*64 + n*16 + li;
      xo[(size_t)row*768 + col] = f2bf(accO[n][r] / accL[r]);
    }
}

extern "C" void kernel_launch(void* const* d_in, const int* in_sizes, int n_in,
                              void* d_out, int out_size, void* d_ws, size_t ws_size,
                              hipStream_t stream){
  const float* tem   = (const float*)d_in[0];
  const float* qin   = (const float*)d_in[1];
  const float* kvin  = (const float*)d_in[2];
  const float* pos   = (const float*)d_in[3];
  const float* ln1qg = (const float*)d_in[4];
  const float* ln1qb = (const float*)d_in[5];
  const float* ln1kg = (const float*)d_in[6];
  const float* ln1kb = (const float*)d_in[7];
  const float* Wq    = (const float*)d_in[8];
  const float* bq    = (const float*)d_in[9];
  const float* Wkv   = (const float*)d_in[10];
  const float* bkv   = (const float*)d_in[11];
  const float* Wp    = (const float*)d_in[12];
  const float* bp    = (const float*)d_in[13];
  const float* ln2g  = (const float*)d_in[14];
  const float* ln2b  = (const float*)d_in[15];
  const float* W1    = (const float*)d_in[16];
  const float* b1    = (const float*)d_in[17];
  const float* W2    = (const float*)d_in[18];
  const float* b2    = (const float*)d_in[19];

  char* ws = (char*)d_ws; size_t off = 0;
  auto alloc = [&](size_t n){ char* p = ws + off; off = (off + n + 255) & ~(size_t)255; return p; };
  __hip_bfloat16* WqT  = (__hip_bfloat16*)alloc((size_t)768*768*2);
  __hip_bfloat16* WkvT = (__hip_bfloat16*)alloc((size_t)1536*768*2);
  __hip_bfloat16* WpT  = (__hip_bfloat16*)alloc((size_t)768*768*2);
  __hip_bfloat16* W1T  = (__hip_bfloat16*)alloc((size_t)3072*768*2);
  __hip_bfloat16* W2T  = (__hip_bfloat16*)alloc((size_t)768*3072*2);
  __hip_bfloat16* qn   = (__hip_bfloat16*)alloc((size_t)4096*768*2);
  char* poolBase = alloc((size_t)5376*768*2*3 + (size_t)4096*768*2); // kvn,kbuf,vt,qhb pool
  __hip_bfloat16* kvn  = (__hip_bfloat16*)poolBase;
  __hip_bfloat16* kbuf = kvn  + (size_t)5376*768;
  __hip_bfloat16* vt   = kbuf + (size_t)5376*768;   // (B*H*64, 1344) = 8.25MB, written by gemm<1>
  __hip_bfloat16* qhb  = vt   + (size_t)5376*768;
  __hip_bfloat16* xat  = (__hip_bfloat16*)alloc((size_t)4096*768*2);
  float*          x1f  = (float*)alloc((size_t)4096*768*4);
  __hip_bfloat16* hln  = qn;    // qn dead after gemm<0>
  __hip_bfloat16* h1   = kvn;   // pool dead after attn

  prep_kernel<<<16384, 256, 0, stream>>>(Wq, Wkv, Wp, W1, W2, WqT, WkvT, WpT, W1T, W2T,
                                         qin, kvin, ln1qg, ln1qb, ln1kg, ln1kb, qn, kvn);

  gemm_gl<64,64,0><<<dim3(64, 12), 256, 0, stream>>>(qn,  WqT,  bq,  4096, 768,  768,  qhb, nullptr, nullptr);
  gemm_gl<64,64,1><<<dim3(84, 24), 256, 0, stream>>>(kvn, WkvT, bkv, 5376, 1536, 768,  kbuf, tem, vt);

  attn_kernel<<<768, 256, 0, stream>>>(qhb, kbuf, vt, pos, xat);

  gemm_gl<64,64,2><<<dim3(64, 12), 256, 0, stream>>>(xat, WpT,  bp,  4096, 768,  768,  x1f, qin, nullptr);
  ln_kernel<<<4096, 256, 0, stream>>>(x1f, ln2g, ln2b, hln);
  gemm_gl<128,128,3><<<dim3(32, 24), 256, 0, stream>>>(hln, W1T,  b1,  4096, 3072, 768,  h1, nullptr, nullptr);
  gemm_gl<64,64,4><<<dim3(64, 12), 256, 0, stream>>>(h1,  W2T,  b2,  4096, 768,  3072, (float*)d_out, x1f, nullptr);
}